// Round 8
// baseline (177.091 us; speedup 1.0000x reference)
//
#include <hip/hip_runtime.h>

typedef short s16x8 __attribute__((ext_vector_type(8)));
typedef float f32x4 __attribute__((ext_vector_type(4)));

__device__ inline unsigned short bf16_rn(float f) {
  unsigned int u = __float_as_uint(f);
  return (unsigned short)((u + 0x7FFFu + ((u >> 16) & 1u)) >> 16);
}
__device__ inline float bf16f(unsigned short h) {
  return __uint_as_float(((unsigned int)h) << 16);
}

// async global->LDS DMA, 16 B per lane; LDS dest = wave-uniform base + lane*16
typedef __attribute__((address_space(3))) unsigned int lds_u32_t;
typedef __attribute__((address_space(1))) const unsigned int g_u32_t;
__device__ __forceinline__ void gload_lds16(const void* g, void* l) {
  __builtin_amdgcn_global_load_lds((g_u32_t*)g, (lds_u32_t*)l, 16, 0, 0);
}

// ---------------------------------------------------------------------------
// Kernel 1: codebook -> 32 superblocks of 16 KB, XOR-swizzled hi/lo bf16.
// Superblock s = [halfA: codes s*16..s*16+15 | halfB: codes 512+s*16..],
// each half-block = [hi 16x128 | lo 16x128] ushorts. Code k: half=k>>9,
// s=(k>>4)&31, r=k&15; row r stores chunk c at slot c^r (conflict-free).
// 32 blocks x 256 thr, 8 lanes/row; also zeroes loss[512] (main atomicAdds).
// ---------------------------------------------------------------------------
__global__ __launch_bounds__(256) void vq_convert_cb(const float* __restrict__ cb,
                                                     unsigned short* __restrict__ cbimg,
                                                     float* __restrict__ cbn,
                                                     float* __restrict__ loss) {
  int tid = threadIdx.x;
  int gid = blockIdx.x * 256 + tid;
  if (gid < 512) loss[gid] = 0.f;
  int k = blockIdx.x * 32 + (tid >> 3);  // 0..1023
  int sub = tid & 7;
  int half = k >> 9, s = (k >> 4) & 31, r = k & 15;
  const float* row = cb + (size_t)k * 128;
  unsigned short* base = cbimg + (size_t)s * 8192 + half * 4096 + r * 128;
  float nrm = 0.f;
#pragma unroll
  for (int cc = 0; cc < 2; ++cc) {
    int c = sub * 2 + cc;
    float4 a = *(const float4*)(row + c * 8);
    float4 b = *(const float4*)(row + c * 8 + 4);
    float v[8] = {a.x, a.y, a.z, a.w, b.x, b.y, b.z, b.w};
    unsigned int hw[4], lw[4];
#pragma unroll
    for (int i = 0; i < 4; ++i) {
      unsigned short h0 = bf16_rn(v[2 * i]), h1 = bf16_rn(v[2 * i + 1]);
      float r0 = v[2 * i] - bf16f(h0), r1 = v[2 * i + 1] - bf16f(h1);
      unsigned short l0 = bf16_rn(r0), l1 = bf16_rn(r1);
      hw[i] = (unsigned)h0 | ((unsigned)h1 << 16);
      lw[i] = (unsigned)l0 | ((unsigned)l1 << 16);
      nrm += v[2 * i] * v[2 * i] + v[2 * i + 1] * v[2 * i + 1];
    }
    int cs = c ^ r;
    *(uint4*)(base + cs * 8) = make_uint4(hw[0], hw[1], hw[2], hw[3]);
    *(uint4*)(base + cs * 8 + 2048) = make_uint4(lw[0], lw[1], lw[2], lw[3]);
  }
  nrm += __shfl_xor(nrm, 1);
  nrm += __shfl_xor(nrm, 2);
  nrm += __shfl_xor(nrm, 4);
  if (sub == 0) cbn[k] = nrm;
}

// ---------------------------------------------------------------------------
// Kernel 2: fused main, split-N x doubled grid. 1024 blocks x 512 thr
// (8 waves). Block owns 64 tokens; waves 0-3 scan codes 0-511, waves 4-7
// codes 512-1023 for the SAME tokens. 8192 waves total (2x every prior
// round) -> grid finally supplies >16 waves/CU; (512,6) = 85-reg budget,
// 16-token state ~70 regs (proven scale), 3 blocks/CU = 24 waves/CU.
// 32 superblock phases through dbuf LDS (32 KB); 3-pass split-bf16 MFMA
// (2 acc chains) + setprio; min/max exact top-2 per half (packed keys);
// epilogue (waves 0-3) rescores the 4-candidate union exactly in fp32;
// per-block loss partial atomicAdded into loss[block>>1] (convert zeroes).
// ---------------------------------------------------------------------------
__global__ __launch_bounds__(512, 6) void vq_main(
    const float* __restrict__ xg, const float* __restrict__ cb,
    const unsigned short* __restrict__ cbimg, const float* __restrict__ cbn,
    float* __restrict__ xq, float* __restrict__ loss) {
  __shared__ __attribute__((aligned(16))) unsigned short sB[2][8192];  // 32 KB
  __shared__ float sNorm[1024];
  __shared__ int sKK[128];  // [half][64 tokens]
  __shared__ float sLoss[4];
  const int tid = threadIdx.x;
  const int wave = tid >> 6, lane = tid & 63;
  const int i0 = lane & 15, q = lane >> 4;
  const int grp = wave >> 2;   // codebook half this wave scans
  const int wv = wave & 3;     // token-group id
  const int tokW = blockIdx.x * 64 + wv * 16;

  // ---- stage codebook norms into LDS (4 KB, 512 thr x float2) ----
  *(float2*)&sNorm[tid * 2] = *(const float2*)(cbn + tid * 2);

  // ---- load own 16 tokens, split fp32 -> bf16 hi + bf16 lo in-register ----
  s16x8 ahi[4], alo[4];
#pragma unroll
  for (int kf = 0; kf < 4; ++kf) {
    const float* p = xg + (size_t)(tokW + i0) * 128 + kf * 32 + q * 8;
    float4 a = *(const float4*)p, b = *(const float4*)(p + 4);
    float v[8] = {a.x, a.y, a.z, a.w, b.x, b.y, b.z, b.w};
    s16x8 h, l;
#pragma unroll
    for (int j = 0; j < 8; ++j) {
      unsigned short hh = bf16_rn(v[j]);
      float rr = v[j] - bf16f(hh);
      h[j] = (short)hh;
      l[j] = (short)bf16_rn(rr);
    }
    ahi[kf] = h;
    alo[kf] = l;
  }

  // B-frag LDS ushort offsets into own half (XOR de-swizzle); lo at +2048
  int boff[4];
#pragma unroll
  for (int ks = 0; ks < 4; ++ks)
    boff[ks] = grp * 4096 + i0 * 128 + (((ks * 4 + q) ^ i0) * 8);

  // ---- async stage superblock 0 (2 x 1KB slices/wave, 8 waves = 16 KB) ----
  const char* gbase = (const char*)cbimg;
  const int so = wave * 2048 + lane * 16;  // per-lane global offset in sblock
  const int su = wave * 2048;              // wave-uniform LDS offset
  {
    const char* g = gbase + so;
    char* l = (char*)&sB[0][0] + su;
    gload_lds16(g, l);
    gload_lds16(g + 1024, l + 1024);
  }

  float d1[4], d2[4];
  int kk12[4];  // k1 | (k2 << 16)
#pragma unroll
  for (int g = 0; g < 4; ++g) {
    d1[g] = 3.4e38f; d2[g] = 3.4e38f; kk12[g] = 0;
  }
  __syncthreads();  // drains vmcnt -> superblock 0 resident; sNorm visible

  const int kbase = grp * 512 + i0;
  for (int t = 0; t < 32; ++t) {
    const int cur = t & 1;
    if (t < 31) {  // async prefetch of superblock t+1 (issued BEFORE compute)
      const char* g = gbase + (t + 1) * 16384 + so;
      char* l = (char*)&sB[1 - cur][0] + su;
      gload_lds16(g, l);
      gload_lds16(g + 1024, l + 1024);
    }
    // two accumulator chains (ILP) summed at the end; selector-only rounding
    f32x4 accA = (f32x4){0.f, 0.f, 0.f, 0.f};
    f32x4 accB = (f32x4){0.f, 0.f, 0.f, 0.f};
#pragma unroll
    for (int ks = 0; ks < 4; ++ks) {
      s16x8 bhi = *(const s16x8*)&sB[cur][boff[ks]];
      s16x8 blo = *(const s16x8*)&sB[cur][boff[ks] + 2048];
      __builtin_amdgcn_s_setprio(1);
      accA = __builtin_amdgcn_mfma_f32_16x16x32_bf16(ahi[ks], bhi, accA, 0, 0, 0);
      accB = __builtin_amdgcn_mfma_f32_16x16x32_bf16(ahi[ks], blo, accB, 0, 0, 0);
      accB = __builtin_amdgcn_mfma_f32_16x16x32_bf16(alo[ks], bhi, accB, 0, 0, 0);
      __builtin_amdgcn_s_setprio(0);
    }
    f32x4 acc = accA + accB;
    // ---- exact top-2 update (min/max form, packed keys);
    //      strict < keeps first-min (ascending k order) ----
    int kc = kbase + t * 16;
    float cn = sNorm[kc];
#pragma unroll
    for (int g = 0; g < 4; ++g) {
      float dd = fmaf(-2.f, acc[g], cn);
      int kp = kk12[g];
      int ok1 = kp & 0xFFFF;
      bool w = dd < d1[g];
      float ld = fmaxf(dd, d1[g]);  // loser of {dd, d1}
      int lk = w ? ok1 : kc;        // loser's key (tie -> new/larger kc)
      d1[g] = fminf(dd, d1[g]);
      int nk1 = w ? kc : ok1;
      bool w2 = ld < d2[g];
      d2[g] = fminf(ld, d2[g]);
      int nk2 = w2 ? lk : (kp >> 16);
      kk12[g] = nk1 | (nk2 << 16);
    }
    __syncthreads();  // waves done reading cur; prefetch into 1-cur drained
  }

  // ---- unpack keys (A-frags dead now; pressure is low here) ----
  int k1[4], k2[4];
#pragma unroll
  for (int g = 0; g < 4; ++g) {
    k1[g] = kk12[g] & 0xFFFF;
    k2[g] = (kk12[g] >> 16) & 0xFFFF;
  }

  // ---- butterfly merge of top-2 across the 16 i0-lanes (lex d,k) ----
#pragma unroll
  for (int off = 1; off < 16; off <<= 1) {
#pragma unroll
    for (int g = 0; g < 4; ++g) {
      float od1 = __shfl_xor(d1[g], off);
      int ok1 = __shfl_xor(k1[g], off);
      float od2 = __shfl_xor(d2[g], off);
      int ok2 = __shfl_xor(k2[g], off);
      bool t1 = (od1 < d1[g]) || (od1 == d1[g] && ok1 < k1[g]);
      float w1d = t1 ? od1 : d1[g];
      int w1k = t1 ? ok1 : k1[g];
      float l1d = t1 ? d1[g] : od1;  // loser of the firsts
      int l1k = t1 ? k1[g] : ok1;
      float c2d = t1 ? od2 : d2[g];  // winner's own second
      int c2k = t1 ? ok2 : k2[g];
      bool t2 = (l1d < c2d) || (l1d == c2d && l1k < c2k);
      d1[g] = w1d; k1[g] = w1k;
      d2[g] = t2 ? l1d : c2d;
      k2[g] = t2 ? l1k : c2k;
    }
  }

  if (i0 == 0) {
#pragma unroll
    for (int g = 0; g < 4; ++g)
      sKK[grp * 64 + wv * 16 + q * 4 + g] = k1[g] | (k2[g] << 10);
  }
  __syncthreads();

  // ---- epilogue (waves 0-3; 16 tokens each): exact fp32 rescore of the
  //      4-candidate union, winner re-read (L2-hot) + coalesced xq store ----
  float lacc = 0.f;
  if (wave < 4) {
    int ltok = wave * 16 + i0;  // 0..63
    int a = sKK[ltok], b = sKK[64 + ltok];
    int ca = a & 1023, cb2 = (a >> 10) & 1023;
    int cc = b & 1023, cd = (b >> 10) & 1023;
    size_t token = (size_t)blockIdx.x * 64 + ltok;
    float s1 = 0.f, s2 = 0.f, s3 = 0.f, s4 = 0.f;
#pragma unroll
    for (int kf = 0; kf < 4; ++kf) {
      const float* xp = xg + token * 128 + kf * 32 + q * 8;
      float4 xa = *(const float4*)xp, xb = *(const float4*)(xp + 4);
      const float* p1 = cb + (size_t)ca * 128 + kf * 32 + q * 8;
      float4 ua = *(const float4*)p1, ub = *(const float4*)(p1 + 4);
      const float* p2 = cb + (size_t)cb2 * 128 + kf * 32 + q * 8;
      float4 va = *(const float4*)p2, vb = *(const float4*)(p2 + 4);
      const float* p3 = cb + (size_t)cc * 128 + kf * 32 + q * 8;
      float4 wa = *(const float4*)p3, wb = *(const float4*)(p3 + 4);
      const float* p4 = cb + (size_t)cd * 128 + kf * 32 + q * 8;
      float4 ya = *(const float4*)p4, yb = *(const float4*)(p4 + 4);
      float xv[8] = {xa.x, xa.y, xa.z, xa.w, xb.x, xb.y, xb.z, xb.w};
      float e1[8] = {ua.x, ua.y, ua.z, ua.w, ub.x, ub.y, ub.z, ub.w};
      float e2[8] = {va.x, va.y, va.z, va.w, vb.x, vb.y, vb.z, vb.w};
      float e3[8] = {wa.x, wa.y, wa.z, wa.w, wb.x, wb.y, wb.z, wb.w};
      float e4[8] = {ya.x, ya.y, ya.z, ya.w, yb.x, yb.y, yb.z, yb.w};
#pragma unroll
      for (int j = 0; j < 8; ++j) {
        float f1 = xv[j] - e1[j];
        float f2 = xv[j] - e2[j];
        float f3 = xv[j] - e3[j];
        float f4 = xv[j] - e4[j];
        s1 = fmaf(f1, f1, s1);
        s2 = fmaf(f2, f2, s2);
        s3 = fmaf(f3, f3, s3);
        s4 = fmaf(f4, f4, s4);
      }
    }
    s1 += __shfl_xor(s1, 16); s1 += __shfl_xor(s1, 32);
    s2 += __shfl_xor(s2, 16); s2 += __shfl_xor(s2, 32);
    s3 += __shfl_xor(s3, 16); s3 += __shfl_xor(s3, 32);
    s4 += __shfl_xor(s4, 16); s4 += __shfl_xor(s4, 32);
    // pick min distance, ties -> lowest index (argmin-first semantics)
    float bs = s1; int bk = ca;
    bool u2 = (s2 < bs) || (s2 == bs && cb2 < bk); bs = u2 ? s2 : bs; bk = u2 ? cb2 : bk;
    bool u3 = (s3 < bs) || (s3 == bs && cc < bk);  bs = u3 ? s3 : bs; bk = u3 ? cc : bk;
    bool u4 = (s4 < bs) || (s4 == bs && cd < bk);  bs = u4 ? s4 : bs; bk = u4 ? cd : bk;
#pragma unroll
    for (int kf = 0; kf < 4; ++kf) {
      const float* pw = cb + (size_t)bk * 128 + kf * 32 + q * 8;
      float4 wa = *(const float4*)pw, wb = *(const float4*)(pw + 4);
      float* op = xq + token * 128 + kf * 32 + q * 8;
      *(float4*)op = wa;
      *(float4*)(op + 4) = wb;
    }
    if (q == 0) lacc += bs;
#pragma unroll
    for (int off = 1; off < 64; off <<= 1) lacc += __shfl_xor(lacc, off);
    if (lane == 0) sLoss[wave] = lacc;
  }
  __syncthreads();
  // block covers half a (b,s) slice (64 of 128 tokens): one atomic per
  // block into loss[block>>1]; loss[] zeroed by vq_convert_cb.
  if (tid == 0) {
    float s = sLoss[0] + sLoss[1] + sLoss[2] + sLoss[3];
    atomicAdd(&loss[blockIdx.x >> 1], s * (1.25f / 16384.f));
  }
}

// ---------------------------------------------------------------------------
extern "C" void kernel_launch(void* const* d_in, const int* in_sizes, int n_in,
                              void* d_out, int out_size, void* d_ws, size_t ws_size,
                              hipStream_t stream) {
  const float* x = (const float*)d_in[0];   // [8,64,128,128] fp32
  const float* cb = (const float*)d_in[1];  // [1024,128] fp32
  float* out = (float*)d_out;
  float* xq = out;
  float* loss = out + (size_t)8 * 64 * 128 * 128;  // 512 floats

  // ws: cbimg 512 KB | cbn 4 KB
  unsigned short* cbimg = (unsigned short*)d_ws;
  float* cbn = (float*)(cbimg + (size_t)1024 * 128 * 2);

  vq_convert_cb<<<32, 256, 0, stream>>>(cb, cbimg, cbn, loss);
  vq_main<<<1024, 512, 0, stream>>>(x, cb, cbimg, cbn, xq, loss);
}

// Round 9
// 155.801 us; speedup vs baseline: 1.1367x; 1.1367x over previous
//
#include <hip/hip_runtime.h>

typedef short s16x8 __attribute__((ext_vector_type(8)));
typedef float f32x4 __attribute__((ext_vector_type(4)));

__device__ inline unsigned short bf16_rn(float f) {
  unsigned int u = __float_as_uint(f);
  return (unsigned short)((u + 0x7FFFu + ((u >> 16) & 1u)) >> 16);
}
__device__ inline float bf16f(unsigned short h) {
  return __uint_as_float(((unsigned int)h) << 16);
}

// async global->LDS DMA, 16 B per lane; LDS dest = wave-uniform base + lane*16
typedef __attribute__((address_space(3))) unsigned int lds_u32_t;
typedef __attribute__((address_space(1))) const unsigned int g_u32_t;
__device__ __forceinline__ void gload_lds16(const void* g, void* l) {
  __builtin_amdgcn_global_load_lds((g_u32_t*)g, (lds_u32_t*)l, 16, 0, 0);
}

// lexicographic (d,k) compare-swap / min helpers for the top-4 merge
__device__ __forceinline__ void lexswap(float& da, int& ka, float& db, int& kb) {
  bool sw = (db < da) || (db == da && kb < ka);
  float nd = sw ? db : da, xd = sw ? da : db;
  int nk = sw ? kb : ka, xk = sw ? ka : kb;
  da = nd; db = xd; ka = nk; kb = xk;
}
__device__ __forceinline__ void lexmin2(float& da, int& ka, float ob, int okb) {
  bool sw = (ob < da) || (ob == da && okb < ka);
  da = sw ? ob : da; ka = sw ? okb : ka;
}

// ---------------------------------------------------------------------------
// Kernel 1: codebook -> 64-code-tiled XOR-swizzled HI-ONLY bf16 image (256 KB)
// + exact fp32 norms. Tile = 64x128 ushort = 16 KB; row r stores 8-dim chunk
// c at chunk slot c ^ (r & 15) (conflict-free ds_read_b128 later).
// ---------------------------------------------------------------------------
__global__ __launch_bounds__(64) void vq_convert_cb(const float* __restrict__ cb,
                                                    unsigned short* __restrict__ cbimg,
                                                    float* __restrict__ cbn) {
  int k = blockIdx.x * 64 + threadIdx.x;  // 0..1023
  int tile = k >> 6, r = k & 63, sm = r & 15;
  const float* row = cb + (size_t)k * 128;
  float nrm = 0.f;
#pragma unroll
  for (int c = 0; c < 16; ++c) {
    float4 a = *(const float4*)(row + c * 8);
    float4 b = *(const float4*)(row + c * 8 + 4);
    float v[8] = {a.x, a.y, a.z, a.w, b.x, b.y, b.z, b.w};
    unsigned int hw[4];
#pragma unroll
    for (int i = 0; i < 4; ++i) {
      unsigned short h0 = bf16_rn(v[2 * i]), h1 = bf16_rn(v[2 * i + 1]);
      hw[i] = (unsigned)h0 | ((unsigned)h1 << 16);
      nrm += v[2 * i] * v[2 * i] + v[2 * i + 1] * v[2 * i + 1];
    }
    int cs = c ^ sm;
    *(uint4*)(cbimg + (size_t)tile * 8192 + r * 128 + cs * 8) =
        make_uint4(hw[0], hw[1], hw[2], hw[3]);
  }
  cbn[k] = nrm;
}

// ---------------------------------------------------------------------------
// Kernel 2: fused main. R1 shell (512 blocks x 512 thr, 8 waves, (512,4),
// 16 tokens/wave, 16 phases x 64-code tiles, dbuf) with 2-PASS MFMA:
// acc = (x_hi + x_lo) . e_hi  — B lo plane DROPPED. Distance error is only
// 2 x.e_lo (sigma ~0.05 vs ~9 candidate spacing); rescue = per-lane top-2
// (unchanged hot loop) -> top-4 bitonic butterfly merge (one-time) ->
// exact fp32 rescore of 4 candidates (R8-proven epilogue). Per phase:
// MFMA 48->32, LDS B-reads 32->16 KB/wave, staged bytes halved. LDS 37.9 KB.
// ---------------------------------------------------------------------------
__global__ __launch_bounds__(512, 4) void vq_main(
    const float* __restrict__ xg, const float* __restrict__ cb,
    const unsigned short* __restrict__ cbimg, const float* __restrict__ cbn,
    float* __restrict__ xq, float* __restrict__ loss) {
  __shared__ __attribute__((aligned(16))) unsigned short sB[2][8192];  // 32 KB
  __shared__ float sNorm[1024];
  __shared__ int sKa[128], sKb[128];  // k1|k2<<16, k3|k4<<16 per token
  __shared__ float sLoss[8];
  const int tid = threadIdx.x;
  const int wave = tid >> 6, lane = tid & 63;
  const int i0 = lane & 15, q = lane >> 4;
  const int tokW = blockIdx.x * 128 + wave * 16;

  // ---- stage codebook norms into LDS (4 KB, 512 thr x float2) ----
  *(float2*)&sNorm[tid * 2] = *(const float2*)(cbn + tid * 2);

  // ---- load own 16 tokens, split fp32 -> bf16 hi + bf16 lo in-register ----
  s16x8 ahi[4], alo[4];
#pragma unroll
  for (int kf = 0; kf < 4; ++kf) {
    const float* p = xg + (size_t)(tokW + i0) * 128 + kf * 32 + q * 8;
    float4 a = *(const float4*)p, b = *(const float4*)(p + 4);
    float v[8] = {a.x, a.y, a.z, a.w, b.x, b.y, b.z, b.w};
    s16x8 h, l;
#pragma unroll
    for (int j = 0; j < 8; ++j) {
      unsigned short hh = bf16_rn(v[j]);
      float rr = v[j] - bf16f(hh);
      h[j] = (short)hh;
      l[j] = (short)bf16_rn(rr);
    }
    ahi[kf] = h;
    alo[kf] = l;
  }

  // B-frag base offsets (c=0): row i0, chunk slot XOR de-swizzle; c adds 2048
  int boff[4];
#pragma unroll
  for (int ks = 0; ks < 4; ++ks)
    boff[ks] = i0 * 128 + (((ks * 4 + q) ^ i0) * 8);

  // ---- async stage tile 0 (hi-only 16 KB: 2 x 1KB slices per wave) ----
  const char* gbase = (const char*)cbimg;
  const int so = wave * 2048 + lane * 16;  // per-lane global offset in tile
  const int su = wave * 2048;              // wave-uniform LDS offset
  {
    const char* g = gbase + so;
    char* l = (char*)&sB[0][0] + su;
    gload_lds16(g, l);
    gload_lds16(g + 1024, l + 1024);
  }

  float d1[4], d2[4];
  int kk12[4];  // k1 | (k2 << 16)
#pragma unroll
  for (int g = 0; g < 4; ++g) {
    d1[g] = 3.4e38f; d2[g] = 3.4e38f; kk12[g] = 0;
  }
  __syncthreads();  // drains vmcnt -> tile 0 resident; sNorm visible

  for (int t = 0; t < 16; ++t) {
    const int cur = t & 1;
    if (t < 15) {  // async prefetch of tile t+1 (issued BEFORE compute)
      const char* g = gbase + (t + 1) * 16384 + so;
      char* l = (char*)&sB[1 - cur][0] + su;
      gload_lds16(g, l);
      gload_lds16(g + 1024, l + 1024);
    }
    f32x4 acc[4];
#pragma unroll
    for (int c = 0; c < 4; ++c) acc[c] = (f32x4){0.f, 0.f, 0.f, 0.f};

#pragma unroll
    for (int ks = 0; ks < 4; ++ks) {
#pragma unroll
      for (int c = 0; c < 4; ++c) {
        s16x8 bhi = *(const s16x8*)&sB[cur][boff[ks] + c * 2048];
        __builtin_amdgcn_s_setprio(1);
        acc[c] = __builtin_amdgcn_mfma_f32_16x16x32_bf16(ahi[ks], bhi, acc[c], 0, 0, 0);
        acc[c] = __builtin_amdgcn_mfma_f32_16x16x32_bf16(alo[ks], bhi, acc[c], 0, 0, 0);
        __builtin_amdgcn_s_setprio(0);
      }
    }
    // ---- approx top-2 update (min/max form, packed keys);
    //      candidates arrive k-ascending, strict < keeps first-min ----
#pragma unroll
    for (int c = 0; c < 4; ++c) {
      int kc = t * 64 + c * 16 + i0;
      float cn = sNorm[kc];
#pragma unroll
      for (int g = 0; g < 4; ++g) {
        float dd = fmaf(-2.f, acc[c][g], cn);
        int kp = kk12[g * 0 + g];  // (kept simple: kk12[g])
        kp = kk12[g];
        int ok1 = kp & 0xFFFF;
        bool w = dd < d1[g];
        float ld = fmaxf(dd, d1[g]);  // loser of {dd, d1}
        int lk = w ? ok1 : kc;        // loser's key (tie -> new/larger kc)
        d1[g] = fminf(dd, d1[g]);
        int nk1 = w ? kc : ok1;
        bool w2 = ld < d2[g];
        d2[g] = fminf(ld, d2[g]);
        int nk2 = w2 ? lk : (kp >> 16);
        kk12[g] = nk1 | (nk2 << 16);
      }
    }
    __syncthreads();  // waves done reading cur; prefetch into 1-cur drained
  }

  // ---- unpack to 4-deep sorted lists (pads at +inf) ----
  int k1[4], k2[4], k3[4], k4[4];
  float d3[4], d4[4];
#pragma unroll
  for (int g = 0; g < 4; ++g) {
    k1[g] = kk12[g] & 0xFFFF;
    k2[g] = (kk12[g] >> 16) & 0xFFFF;
    d3[g] = 3.4e38f; d4[g] = 3.4e38f; k3[g] = 0; k4[g] = 0;
  }

  // ---- butterfly top-4 merge across the 16 i0-lanes (lex d,k).
  //      both lists sorted asc; bitonic head-tail select + 5-comparator sort.
#pragma unroll
  for (int off = 1; off < 16; off <<= 1) {
#pragma unroll
    for (int g = 0; g < 4; ++g) {
      float ob0 = __shfl_xor(d1[g], off), ob1 = __shfl_xor(d2[g], off);
      float ob2 = __shfl_xor(d3[g], off), ob3 = __shfl_xor(d4[g], off);
      int ok0 = __shfl_xor(k1[g], off), ok1 = __shfl_xor(k2[g], off);
      int ok2 = __shfl_xor(k3[g], off), ok3 = __shfl_xor(k4[g], off);
      float m0 = d1[g], m1 = d2[g], m2 = d3[g], m3 = d4[g];
      int n0 = k1[g], n1 = k2[g], n2 = k3[g], n3 = k4[g];
      lexmin2(m0, n0, ob3, ok3);  // a_i vs b_{3-i} -> 4 smallest of union
      lexmin2(m1, n1, ob2, ok2);
      lexmin2(m2, n2, ob1, ok1);
      lexmin2(m3, n3, ob0, ok0);
      lexswap(m0, n0, m2, n2);    // sort the 4
      lexswap(m1, n1, m3, n3);
      lexswap(m0, n0, m1, n1);
      lexswap(m2, n2, m3, n3);
      lexswap(m1, n1, m2, n2);
      d1[g] = m0; d2[g] = m1; d3[g] = m2; d4[g] = m3;
      k1[g] = n0; k2[g] = n1; k3[g] = n2; k4[g] = n3;
    }
  }

  if (i0 == 0) {
#pragma unroll
    for (int g = 0; g < 4; ++g) {
      sKa[wave * 16 + q * 4 + g] = k1[g] | (k2[g] << 16);
      sKb[wave * 16 + q * 4 + g] = k3[g] | (k4[g] << 16);
    }
  }
  __syncthreads();

  // ---- epilogue: exact fp32 rescore of the 4-candidate union,
  //      winner re-read (L2-hot) + coalesced xq store; block-local loss ----
  float lacc = 0.f;
  {
    int ltok = wave * 16 + i0;
    int a = sKa[ltok], b = sKb[ltok];
    int ca = a & 0xFFFF, cb2 = (a >> 16) & 0xFFFF;
    int cc = b & 0xFFFF, cd = (b >> 16) & 0xFFFF;
    size_t token = (size_t)tokW + i0;
    float s1 = 0.f, s2 = 0.f, s3 = 0.f, s4 = 0.f;
#pragma unroll
    for (int kf = 0; kf < 4; ++kf) {
      const float* xp = xg + token * 128 + kf * 32 + q * 8;
      float4 xa = *(const float4*)xp, xb = *(const float4*)(xp + 4);
      const float* p1 = cb + (size_t)ca * 128 + kf * 32 + q * 8;
      float4 ua = *(const float4*)p1, ub = *(const float4*)(p1 + 4);
      const float* p2 = cb + (size_t)cb2 * 128 + kf * 32 + q * 8;
      float4 va = *(const float4*)p2, vb = *(const float4*)(p2 + 4);
      const float* p3 = cb + (size_t)cc * 128 + kf * 32 + q * 8;
      float4 wa = *(const float4*)p3, wb = *(const float4*)(p3 + 4);
      const float* p4 = cb + (size_t)cd * 128 + kf * 32 + q * 8;
      float4 ya = *(const float4*)p4, yb = *(const float4*)(p4 + 4);
      float xv[8] = {xa.x, xa.y, xa.z, xa.w, xb.x, xb.y, xb.z, xb.w};
      float e1[8] = {ua.x, ua.y, ua.z, ua.w, ub.x, ub.y, ub.z, ub.w};
      float e2[8] = {va.x, va.y, va.z, va.w, vb.x, vb.y, vb.z, vb.w};
      float e3[8] = {wa.x, wa.y, wa.z, wa.w, wb.x, wb.y, wb.z, wb.w};
      float e4[8] = {ya.x, ya.y, ya.z, ya.w, yb.x, yb.y, yb.z, yb.w};
#pragma unroll
      for (int j = 0; j < 8; ++j) {
        float f1 = xv[j] - e1[j];
        float f2 = xv[j] - e2[j];
        float f3 = xv[j] - e3[j];
        float f4 = xv[j] - e4[j];
        s1 = fmaf(f1, f1, s1);
        s2 = fmaf(f2, f2, s2);
        s3 = fmaf(f3, f3, s3);
        s4 = fmaf(f4, f4, s4);
      }
    }
    s1 += __shfl_xor(s1, 16); s1 += __shfl_xor(s1, 32);
    s2 += __shfl_xor(s2, 16); s2 += __shfl_xor(s2, 32);
    s3 += __shfl_xor(s3, 16); s3 += __shfl_xor(s3, 32);
    s4 += __shfl_xor(s4, 16); s4 += __shfl_xor(s4, 32);
    // pick min distance, ties -> lowest index (argmin-first semantics)
    float bs = s1; int bk = ca;
    bool u2 = (s2 < bs) || (s2 == bs && cb2 < bk); bs = u2 ? s2 : bs; bk = u2 ? cb2 : bk;
    bool u3 = (s3 < bs) || (s3 == bs && cc < bk);  bs = u3 ? s3 : bs; bk = u3 ? cc : bk;
    bool u4 = (s4 < bs) || (s4 == bs && cd < bk);  bs = u4 ? s4 : bs; bk = u4 ? cd : bk;
#pragma unroll
    for (int kf = 0; kf < 4; ++kf) {
      const float* pw = cb + (size_t)bk * 128 + kf * 32 + q * 8;
      float4 wa = *(const float4*)pw, wb = *(const float4*)(pw + 4);
      float* op = xq + token * 128 + kf * 32 + q * 8;
      *(float4*)op = wa;
      *(float4*)(op + 4) = wb;
    }
    if (q == 0) lacc += bs;
  }
#pragma unroll
  for (int off = 1; off < 64; off <<= 1) lacc += __shfl_xor(lacc, off);
  if (lane == 0) sLoss[wave] = lacc;
  __syncthreads();
  // block fully owns loss[blockIdx.x] (128 tokens = one (b,s) slice)
  if (tid == 0) {
    float s = 0.f;
#pragma unroll
    for (int w = 0; w < 8; ++w) s += sLoss[w];
    loss[blockIdx.x] = s * (1.25f / 16384.f);
  }
}

// ---------------------------------------------------------------------------
extern "C" void kernel_launch(void* const* d_in, const int* in_sizes, int n_in,
                              void* d_out, int out_size, void* d_ws, size_t ws_size,
                              hipStream_t stream) {
  const float* x = (const float*)d_in[0];   // [8,64,128,128] fp32
  const float* cb = (const float*)d_in[1];  // [1024,128] fp32
  float* out = (float*)d_out;
  float* xq = out;
  float* loss = out + (size_t)8 * 64 * 128 * 128;  // 512 floats

  // ws: cbimg (hi-only) 256 KB | cbn 4 KB
  unsigned short* cbimg = (unsigned short*)d_ws;
  float* cbn = (float*)(cbimg + (size_t)1024 * 128);

  vq_convert_cb<<<16, 64, 0, stream>>>(cb, cbimg, cbn);
  vq_main<<<512, 512, 0, stream>>>(x, cb, cbimg, cbn, xq, loss);
}

// Round 10
// 152.792 us; speedup vs baseline: 1.1590x; 1.0197x over previous
//
#include <hip/hip_runtime.h>

typedef short s16x8 __attribute__((ext_vector_type(8)));
typedef float f32x4 __attribute__((ext_vector_type(4)));

__device__ inline unsigned short bf16_rn(float f) {
  unsigned int u = __float_as_uint(f);
  return (unsigned short)((u + 0x7FFFu + ((u >> 16) & 1u)) >> 16);
}
__device__ inline float bf16f(unsigned short h) {
  return __uint_as_float(((unsigned int)h) << 16);
}

// async global->LDS DMA, 16 B per lane; LDS dest = wave-uniform base + lane*16
typedef __attribute__((address_space(3))) unsigned int lds_u32_t;
typedef __attribute__((address_space(1))) const unsigned int g_u32_t;
__device__ __forceinline__ void gload_lds16(const void* g, void* l) {
  __builtin_amdgcn_global_load_lds((g_u32_t*)g, (lds_u32_t*)l, 16, 0, 0);
}

// lexicographic (d,k) compare-swap / min helpers for the top-4 merge
__device__ __forceinline__ void lexswap(float& da, int& ka, float& db, int& kb) {
  bool sw = (db < da) || (db == da && kb < ka);
  float nd = sw ? db : da, xd = sw ? da : db;
  int nk = sw ? kb : ka, xk = sw ? ka : kb;
  da = nd; db = xd; ka = nk; kb = xk;
}
__device__ __forceinline__ void lexmin2(float& da, int& ka, float ob, int okb) {
  bool sw = (ob < da) || (ob == da && okb < ka);
  da = sw ? ob : da; ka = sw ? okb : ka;
}

// ---------------------------------------------------------------------------
// Kernel 1: codebook -> 64-code-tiled XOR-swizzled HI-ONLY bf16 image (256 KB)
// + exact fp32 norms. Tile = 64x128 ushort = 16 KB; row r stores 8-dim chunk
// c at chunk slot c ^ (r & 15) (conflict-free ds_read_b128 later).
// ---------------------------------------------------------------------------
__global__ __launch_bounds__(64) void vq_convert_cb(const float* __restrict__ cb,
                                                    unsigned short* __restrict__ cbimg,
                                                    float* __restrict__ cbn) {
  int k = blockIdx.x * 64 + threadIdx.x;  // 0..1023
  int tile = k >> 6, r = k & 63, sm = r & 15;
  const float* row = cb + (size_t)k * 128;
  float nrm = 0.f;
#pragma unroll
  for (int c = 0; c < 16; ++c) {
    float4 a = *(const float4*)(row + c * 8);
    float4 b = *(const float4*)(row + c * 8 + 4);
    float v[8] = {a.x, a.y, a.z, a.w, b.x, b.y, b.z, b.w};
    unsigned int hw[4];
#pragma unroll
    for (int i = 0; i < 4; ++i) {
      unsigned short h0 = bf16_rn(v[2 * i]), h1 = bf16_rn(v[2 * i + 1]);
      hw[i] = (unsigned)h0 | ((unsigned)h1 << 16);
      nrm += v[2 * i] * v[2 * i] + v[2 * i + 1] * v[2 * i + 1];
    }
    int cs = c ^ sm;
    *(uint4*)(cbimg + (size_t)tile * 8192 + r * 128 + cs * 8) =
        make_uint4(hw[0], hw[1], hw[2], hw[3]);
  }
  cbn[k] = nrm;
}

// ---------------------------------------------------------------------------
// Kernel 2: fused main. R1's PROVEN schedule (512 blocks x 512 thr, 8 waves,
// (512,4), 16 tokens/wave, 16 phases x 64-code tiles, dbuf, BATCHED B-frag
// reads per ks then MFMA cluster with setprio OUTSIDE the read batch —
// R9's per-frag read+setprio interleave exposed ~120cy ds_read latency
// serially and lost 24 µs) x R9's PROVEN work cut (2-pass hi-only MFMA:
// acc = (x_hi+x_lo).e_hi, B lo plane dropped; top-4 bitonic butterfly +
// exact fp32 rescore of 4 candidates rescues the argmin — absmax identical).
// Per phase vs R1: ds_reads 32->16, MFMA 48->32, staged 32->16 KB.
// ---------------------------------------------------------------------------
__global__ __launch_bounds__(512, 4) void vq_main(
    const float* __restrict__ xg, const float* __restrict__ cb,
    const unsigned short* __restrict__ cbimg, const float* __restrict__ cbn,
    float* __restrict__ xq, float* __restrict__ loss) {
  __shared__ __attribute__((aligned(16))) unsigned short sB[2][8192];  // 32 KB
  __shared__ float sNorm[1024];
  __shared__ int sKa[128], sKb[128];  // k1|k2<<16, k3|k4<<16 per token
  __shared__ float sLoss[8];
  const int tid = threadIdx.x;
  const int wave = tid >> 6, lane = tid & 63;
  const int i0 = lane & 15, q = lane >> 4;
  const int tokW = blockIdx.x * 128 + wave * 16;

  // ---- stage codebook norms into LDS (4 KB, 512 thr x float2) ----
  *(float2*)&sNorm[tid * 2] = *(const float2*)(cbn + tid * 2);

  // ---- load own 16 tokens, split fp32 -> bf16 hi + bf16 lo in-register ----
  s16x8 ahi[4], alo[4];
#pragma unroll
  for (int kf = 0; kf < 4; ++kf) {
    const float* p = xg + (size_t)(tokW + i0) * 128 + kf * 32 + q * 8;
    float4 a = *(const float4*)p, b = *(const float4*)(p + 4);
    float v[8] = {a.x, a.y, a.z, a.w, b.x, b.y, b.z, b.w};
    s16x8 h, l;
#pragma unroll
    for (int j = 0; j < 8; ++j) {
      unsigned short hh = bf16_rn(v[j]);
      float rr = v[j] - bf16f(hh);
      h[j] = (short)hh;
      l[j] = (short)bf16_rn(rr);
    }
    ahi[kf] = h;
    alo[kf] = l;
  }

  // B-frag base offsets (c=0): row i0, chunk slot XOR de-swizzle; c adds 2048
  int boff[4];
#pragma unroll
  for (int ks = 0; ks < 4; ++ks)
    boff[ks] = i0 * 128 + (((ks * 4 + q) ^ i0) * 8);

  // ---- async stage tile 0 (hi-only 16 KB: 2 x 1KB slices per wave) ----
  const char* gbase = (const char*)cbimg;
  const int so = wave * 2048 + lane * 16;  // per-lane global offset in tile
  const int su = wave * 2048;              // wave-uniform LDS offset
  {
    const char* g = gbase + so;
    char* l = (char*)&sB[0][0] + su;
    gload_lds16(g, l);
    gload_lds16(g + 1024, l + 1024);
  }

  float d1[4], d2[4];
  int kk12[4];  // k1 | (k2 << 16)
#pragma unroll
  for (int g = 0; g < 4; ++g) {
    d1[g] = 3.4e38f; d2[g] = 3.4e38f; kk12[g] = 0;
  }
  __syncthreads();  // drains vmcnt -> tile 0 resident; sNorm visible

  for (int t = 0; t < 16; ++t) {
    const int cur = t & 1;
    if (t < 15) {  // async prefetch of tile t+1 (issued BEFORE compute)
      const char* g = gbase + (t + 1) * 16384 + so;
      char* l = (char*)&sB[1 - cur][0] + su;
      gload_lds16(g, l);
      gload_lds16(g + 1024, l + 1024);
    }
    f32x4 acc[4];
#pragma unroll
    for (int c = 0; c < 4; ++c) acc[c] = (f32x4){0.f, 0.f, 0.f, 0.f};

#pragma unroll
    for (int ks = 0; ks < 4; ++ks) {
      // BATCHED reads: 4 ds_read_b128 issued together (R1 pattern), then
      // the MFMA cluster; setprio wraps only the MFMAs.
      s16x8 bhi[4];
#pragma unroll
      for (int c = 0; c < 4; ++c)
        bhi[c] = *(const s16x8*)&sB[cur][boff[ks] + c * 2048];
      __builtin_amdgcn_s_setprio(1);
#pragma unroll
      for (int c = 0; c < 4; ++c)
        acc[c] = __builtin_amdgcn_mfma_f32_16x16x32_bf16(ahi[ks], bhi[c], acc[c], 0, 0, 0);
#pragma unroll
      for (int c = 0; c < 4; ++c)
        acc[c] = __builtin_amdgcn_mfma_f32_16x16x32_bf16(alo[ks], bhi[c], acc[c], 0, 0, 0);
      __builtin_amdgcn_s_setprio(0);
    }
    // ---- approx top-2 update (min/max form, packed keys);
    //      candidates arrive k-ascending, strict < keeps first-min ----
#pragma unroll
    for (int c = 0; c < 4; ++c) {
      int kc = t * 64 + c * 16 + i0;
      float cn = sNorm[kc];
#pragma unroll
      for (int g = 0; g < 4; ++g) {
        float dd = fmaf(-2.f, acc[c][g], cn);
        int kp = kk12[g];
        int ok1 = kp & 0xFFFF;
        bool w = dd < d1[g];
        float ld = fmaxf(dd, d1[g]);  // loser of {dd, d1}
        int lk = w ? ok1 : kc;        // loser's key (tie -> new/larger kc)
        d1[g] = fminf(dd, d1[g]);
        int nk1 = w ? kc : ok1;
        bool w2 = ld < d2[g];
        d2[g] = fminf(ld, d2[g]);
        int nk2 = w2 ? lk : (kp >> 16);
        kk12[g] = nk1 | (nk2 << 16);
      }
    }
    __syncthreads();  // waves done reading cur; prefetch into 1-cur drained
  }

  // ---- unpack to 4-deep sorted lists (pads at +inf) ----
  int k1[4], k2[4], k3[4], k4[4];
  float d3[4], d4[4];
#pragma unroll
  for (int g = 0; g < 4; ++g) {
    k1[g] = kk12[g] & 0xFFFF;
    k2[g] = (kk12[g] >> 16) & 0xFFFF;
    d3[g] = 3.4e38f; d4[g] = 3.4e38f; k3[g] = 0; k4[g] = 0;
  }

  // ---- butterfly top-4 merge across the 16 i0-lanes (lex d,k).
  //      both lists sorted asc; bitonic head-tail select + 5-comparator sort.
#pragma unroll
  for (int off = 1; off < 16; off <<= 1) {
#pragma unroll
    for (int g = 0; g < 4; ++g) {
      float ob0 = __shfl_xor(d1[g], off), ob1 = __shfl_xor(d2[g], off);
      float ob2 = __shfl_xor(d3[g], off), ob3 = __shfl_xor(d4[g], off);
      int ok0 = __shfl_xor(k1[g], off), ok1 = __shfl_xor(k2[g], off);
      int ok2 = __shfl_xor(k3[g], off), ok3 = __shfl_xor(k4[g], off);
      float m0 = d1[g], m1 = d2[g], m2 = d3[g], m3 = d4[g];
      int n0 = k1[g], n1 = k2[g], n2 = k3[g], n3 = k4[g];
      lexmin2(m0, n0, ob3, ok3);  // a_i vs b_{3-i} -> 4 smallest of union
      lexmin2(m1, n1, ob2, ok2);
      lexmin2(m2, n2, ob1, ok1);
      lexmin2(m3, n3, ob0, ok0);
      lexswap(m0, n0, m2, n2);    // sort the 4
      lexswap(m1, n1, m3, n3);
      lexswap(m0, n0, m1, n1);
      lexswap(m2, n2, m3, n3);
      lexswap(m1, n1, m2, n2);
      d1[g] = m0; d2[g] = m1; d3[g] = m2; d4[g] = m3;
      k1[g] = n0; k2[g] = n1; k3[g] = n2; k4[g] = n3;
    }
  }

  if (i0 == 0) {
#pragma unroll
    for (int g = 0; g < 4; ++g) {
      sKa[wave * 16 + q * 4 + g] = k1[g] | (k2[g] << 16);
      sKb[wave * 16 + q * 4 + g] = k3[g] | (k4[g] << 16);
    }
  }
  __syncthreads();

  // ---- epilogue: exact fp32 rescore of the 4-candidate union,
  //      winner re-read (L2-hot) + coalesced xq store; block-local loss ----
  float lacc = 0.f;
  {
    int ltok = wave * 16 + i0;
    int a = sKa[ltok], b = sKb[ltok];
    int ca = a & 0xFFFF, cb2 = (a >> 16) & 0xFFFF;
    int cc = b & 0xFFFF, cd = (b >> 16) & 0xFFFF;
    size_t token = (size_t)tokW + i0;
    float s1 = 0.f, s2 = 0.f, s3 = 0.f, s4 = 0.f;
#pragma unroll
    for (int kf = 0; kf < 4; ++kf) {
      const float* xp = xg + token * 128 + kf * 32 + q * 8;
      float4 xa = *(const float4*)xp, xb = *(const float4*)(xp + 4);
      const float* p1 = cb + (size_t)ca * 128 + kf * 32 + q * 8;
      float4 ua = *(const float4*)p1, ub = *(const float4*)(p1 + 4);
      const float* p2 = cb + (size_t)cb2 * 128 + kf * 32 + q * 8;
      float4 va = *(const float4*)p2, vb = *(const float4*)(p2 + 4);
      const float* p3 = cb + (size_t)cc * 128 + kf * 32 + q * 8;
      float4 wa = *(const float4*)p3, wb = *(const float4*)(p3 + 4);
      const float* p4 = cb + (size_t)cd * 128 + kf * 32 + q * 8;
      float4 ya = *(const float4*)p4, yb = *(const float4*)(p4 + 4);
      float xv[8] = {xa.x, xa.y, xa.z, xa.w, xb.x, xb.y, xb.z, xb.w};
      float e1[8] = {ua.x, ua.y, ua.z, ua.w, ub.x, ub.y, ub.z, ub.w};
      float e2[8] = {va.x, va.y, va.z, va.w, vb.x, vb.y, vb.z, vb.w};
      float e3[8] = {wa.x, wa.y, wa.z, wa.w, wb.x, wb.y, wb.z, wb.w};
      float e4[8] = {ya.x, ya.y, ya.z, ya.w, yb.x, yb.y, yb.z, yb.w};
#pragma unroll
      for (int j = 0; j < 8; ++j) {
        float f1 = xv[j] - e1[j];
        float f2 = xv[j] - e2[j];
        float f3 = xv[j] - e3[j];
        float f4 = xv[j] - e4[j];
        s1 = fmaf(f1, f1, s1);
        s2 = fmaf(f2, f2, s2);
        s3 = fmaf(f3, f3, s3);
        s4 = fmaf(f4, f4, s4);
      }
    }
    s1 += __shfl_xor(s1, 16); s1 += __shfl_xor(s1, 32);
    s2 += __shfl_xor(s2, 16); s2 += __shfl_xor(s2, 32);
    s3 += __shfl_xor(s3, 16); s3 += __shfl_xor(s3, 32);
    s4 += __shfl_xor(s4, 16); s4 += __shfl_xor(s4, 32);
    // pick min distance, ties -> lowest index (argmin-first semantics)
    float bs = s1; int bk = ca;
    bool u2 = (s2 < bs) || (s2 == bs && cb2 < bk); bs = u2 ? s2 : bs; bk = u2 ? cb2 : bk;
    bool u3 = (s3 < bs) || (s3 == bs && cc < bk);  bs = u3 ? s3 : bs; bk = u3 ? cc : bk;
    bool u4 = (s4 < bs) || (s4 == bs && cd < bk);  bs = u4 ? s4 : bs; bk = u4 ? cd : bk;
#pragma unroll
    for (int kf = 0; kf < 4; ++kf) {
      const float* pw = cb + (size_t)bk * 128 + kf * 32 + q * 8;
      float4 wa = *(const float4*)pw, wb = *(const float4*)(pw + 4);
      float* op = xq + token * 128 + kf * 32 + q * 8;
      *(float4*)op = wa;
      *(float4*)(op + 4) = wb;
    }
    if (q == 0) lacc += bs;
  }
#pragma unroll
  for (int off = 1; off < 64; off <<= 1) lacc += __shfl_xor(lacc, off);
  if (lane == 0) sLoss[wave] = lacc;
  __syncthreads();
  // block fully owns loss[blockIdx.x] (128 tokens = one (b,s) slice)
  if (tid == 0) {
    float s = 0.f;
#pragma unroll
    for (int w = 0; w < 8; ++w) s += sLoss[w];
    loss[blockIdx.x] = s * (1.25f / 16384.f);
  }
}

// ---------------------------------------------------------------------------
extern "C" void kernel_launch(void* const* d_in, const int* in_sizes, int n_in,
                              void* d_out, int out_size, void* d_ws, size_t ws_size,
                              hipStream_t stream) {
  const float* x = (const float*)d_in[0];   // [8,64,128,128] fp32
  const float* cb = (const float*)d_in[1];  // [1024,128] fp32
  float* out = (float*)d_out;
  float* xq = out;
  float* loss = out + (size_t)8 * 64 * 128 * 128;  // 512 floats

  // ws: cbimg (hi-only) 256 KB | cbn 4 KB
  unsigned short* cbimg = (unsigned short*)d_ws;
  float* cbn = (float*)(cbimg + (size_t)1024 * 128);

  vq_convert_cb<<<16, 64, 0, stream>>>(cb, cbimg, cbn);
  vq_main<<<512, 512, 0, stream>>>(x, cb, cbimg, cbn, xq, loss);
}